// Round 1
// baseline (382.886 us; speedup 1.0000x reference)
//
#include <hip/hip_runtime.h>
#include <math.h>

#define HW   256
#define TILE 64
#define NBLK 1024   // 64 frames * 16 tiles of 64x64
#define BR   72     // hblur rows staged (tile + 2*4 halo)
#define HC   68     // hblur cols / blur rows+cols (tile + 2*2)
#define GR   66     // grad rows+cols (tile + 2*1)

namespace {
// Gaussian(5, std=1) computed in float64 then cast, matching _gaussian_1d
constexpr double kE2  = 0.13533528323661269189;  // exp(-2)
constexpr double kE05 = 0.60653065971263342360;  // exp(-0.5)
constexpr double kSum = 1.0 + 2.0 * kE2 + 2.0 * kE05;
constexpr float G0f = (float)(kE2 / kSum);
constexpr float G1f = (float)(kE05 / kSum);
constexpr float G2f = (float)(1.0 / kSum);
constexpr float RAD2DEG = (float)(180.0 / 3.14159265358979323846);
}

// Neighbor offsets for direction k (cross-correlation with DIR_FILTERS):
// (dy,dx): k0(0,1) k1(1,1) k2(1,0) k3(1,-1) k4(0,-1) k5(-1,-1) k6(-1,0) k7(-1,1)
// Packed as nibbles ((dy+1)<<2)|(dx+1), k0 in the low nibble.
#define DIR_PACK 0x210489A6u

__global__ __launch_bounds__(256, 2)
void canny_tile_kernel(const float* __restrict__ imgA,
                       const float* __restrict__ imgB,
                       float* __restrict__ partials)
{
    __shared__ float s_tmp[BR * HC];   // horizontal gaussian
    __shared__ float s_blur[HC * HC];  // full blur (zero outside image)
    __shared__ float s_grad[GR * GR];  // channel-summed |grad| (zero outside image)
    __shared__ float s_red[4];

    const int tid  = threadIdx.x;
    const int bid  = blockIdx.x;
    const int n    = bid >> 4;           // frame 0..63
    const int tile = bid & 15;
    const int ty0  = (tile >> 2) * TILE;
    const int tx0  = (tile & 3) * TILE;

    const int ox  = tid & 63;            // owned column within tile
    const int oyb = tid >> 6;            // row group 0..3; rows oyb+4k

    float e_first[16];
    float acc = 0.0f;

    for (int img = 0; img < 2; ++img) {
        const float* base = (img == 0 ? imgA : imgB) + (size_t)n * 3 * (HW * HW);
        float gxs[16], gys[16];
        #pragma unroll
        for (int k = 0; k < 16; ++k) { gxs[k] = 0.0f; gys[k] = 0.0f; }

        for (int c = 0; c < 3; ++c) {
            const float* plane = base + c * (HW * HW);
            __syncthreads();  // protect s_tmp (read by prev A2) and s_grad (read by prev Phase B)

            // ---- A1: horizontal 5-tap gaussian -> s_tmp[BR][HC]
            // s_tmp[r][cx] = hblur(y = ty0-4+r, x = tx0-2+cx); zero for y outside image
            for (int i = tid; i < BR * HC; i += 256) {
                const int r  = i / HC;
                const int cx = i - r * HC;
                const int y  = ty0 - 4 + r;
                float h = 0.0f;
                if ((unsigned)y < HW) {
                    const float* row = plane + y * HW;
                    const int x0 = tx0 - 4 + cx;   // first tap
                    if (x0 >= 0 && x0 <= HW - 5) {
                        h = G0f * row[x0]     + G1f * row[x0 + 1] + G2f * row[x0 + 2]
                          + G1f * row[x0 + 3] + G0f * row[x0 + 4];
                    } else {
                        float v0 = ((unsigned)(x0    ) < HW) ? row[x0    ] : 0.0f;
                        float v1 = ((unsigned)(x0 + 1) < HW) ? row[x0 + 1] : 0.0f;
                        float v2 = ((unsigned)(x0 + 2) < HW) ? row[x0 + 2] : 0.0f;
                        float v3 = ((unsigned)(x0 + 3) < HW) ? row[x0 + 3] : 0.0f;
                        float v4 = ((unsigned)(x0 + 4) < HW) ? row[x0 + 4] : 0.0f;
                        h = G0f*v0 + G1f*v1 + G2f*v2 + G1f*v3 + G0f*v4;
                    }
                }
                s_tmp[i] = h;
            }
            __syncthreads();

            // ---- A2: vertical 5-tap gaussian -> s_blur[HC][HC]
            // Sobel zero-pads BLUR, so blur outside the image must be exactly 0.
            for (int i = tid; i < HC * HC; i += 256) {
                const int r  = i / HC;
                const int cx = i - r * HC;
                const int y  = ty0 - 2 + r;
                const int x  = tx0 - 2 + cx;
                float v = 0.0f;
                if ((unsigned)y < HW && (unsigned)x < HW) {
                    v = G0f * s_tmp[i]          + G1f * s_tmp[i + HC]
                      + G2f * s_tmp[i + 2 * HC] + G1f * s_tmp[i + 3 * HC]
                      + G0f * s_tmp[i + 4 * HC];
                }
                s_blur[i] = v;
            }
            __syncthreads();

            // ---- A3: sobel magnitude, accumulated over channels -> s_grad[GR][GR]
            // DIR conv zero-pads grad_mag, so grad outside the image must be 0.
            for (int i = tid; i < GR * GR; i += 256) {
                const int r  = i / GR;
                const int cc = i - r * GR;
                const int y  = ty0 - 1 + r;
                const int x  = tx0 - 1 + cc;
                float gmag = 0.0f;
                if ((unsigned)y < HW && (unsigned)x < HW) {
                    const float* b = &s_blur[r * HC + cc];
                    const float b00 = b[0],        b01 = b[1],          b02 = b[2];
                    const float b10 = b[HC],                            b12 = b[HC + 2];
                    const float b20 = b[2 * HC],   b21 = b[2 * HC + 1], b22 = b[2 * HC + 2];
                    const float gx = (b00 + 2.0f * b10 + b20) - (b02 + 2.0f * b12 + b22);
                    const float gy = (b00 + 2.0f * b01 + b02) - (b20 + 2.0f * b21 + b22);
                    gmag = sqrtf(gx * gx + gy * gy);
                }
                if (c == 0) s_grad[i] = gmag;
                else        s_grad[i] += gmag;
            }

            // ---- A4: accumulate channel-summed gx, gy at owned pixels (registers)
            #pragma unroll
            for (int k = 0; k < 16; ++k) {
                const int oy = oyb + 4 * k;
                const float* b = &s_blur[(oy + 1) * HC + (ox + 1)];
                const float b00 = b[0],        b01 = b[1],          b02 = b[2];
                const float b10 = b[HC],                            b12 = b[HC + 2];
                const float b20 = b[2 * HC],   b21 = b[2 * HC + 1], b22 = b[2 * HC + 2];
                gxs[k] += (b00 + 2.0f * b10 + b20) - (b02 + 2.0f * b12 + b22);
                gys[k] += (b00 + 2.0f * b01 + b02) - (b20 + 2.0f * b21 + b22);
            }
        }
        __syncthreads();  // s_grad complete for all channels

        // ---- Phase B: orientation NMS + threshold at owned 64x64 pixels
        #pragma unroll
        for (int k = 0; k < 16; ++k) {
            const int oy = oyb + 4 * k;
            const float gc    = s_grad[(oy + 1) * GR + (ox + 1)];
            const float theta = atan2f(gys[k], gxs[k]);
            const float ori   = theta * RAD2DEG + 180.0f;       // [0, 360]
            const float t     = rintf(ori / 45.0f);             // round-half-even, 0..8
            const int   kp    = ((int)t) & 7;                   // mod 8 (handles 8 -> 0)
            const unsigned e4 = (DIR_PACK >> (4 * kp)) & 15u;
            const int dy = (int)(e4 >> 2) - 1;
            const int dx = (int)(e4 & 3u) - 1;
            // neighbor at k+4 is exactly the negated offset
            const float pos = gc - s_grad[(oy + 1 + dy) * GR + (ox + 1 + dx)];
            const float neg = gc - s_grad[(oy + 1 - dy) * GR + (ox + 1 - dx)];
            const float thin = (fminf(pos, neg) > 0.0f) ? gc : 0.0f;
            const float e    = (thin < 2.0f) ? 0.0f : thin;
            if (img == 0) e_first[k] = e;
            else          acc += fabsf(e - e_first[k]);
        }
        __syncthreads();  // s_grad/s_tmp reused by next image
    }

    // ---- deterministic block reduction
    #pragma unroll
    for (int off = 32; off > 0; off >>= 1) acc += __shfl_down(acc, off, 64);
    if ((tid & 63) == 0) s_red[tid >> 6] = acc;
    __syncthreads();
    if (tid == 0) partials[bid] = (s_red[0] + s_red[1]) + (s_red[2] + s_red[3]);
}

__global__ void final_reduce_kernel(const float* __restrict__ partials,
                                    float* __restrict__ out)
{
    __shared__ float s_red[4];
    const int tid = threadIdx.x;  // 256 threads
    float v = 0.0f;
    #pragma unroll
    for (int j = 0; j < 4; ++j) v += partials[tid + 256 * j];
    #pragma unroll
    for (int off = 32; off > 0; off >>= 1) v += __shfl_down(v, off, 64);
    if ((tid & 63) == 0) s_red[tid >> 6] = v;
    __syncthreads();
    if (tid == 0)
        out[0] = ((s_red[0] + s_red[1]) + (s_red[2] + s_red[3])) * (1.0f / 4194304.0f);
}

extern "C" void kernel_launch(void* const* d_in, const int* in_sizes, int n_in,
                              void* d_out, int out_size, void* d_ws, size_t ws_size,
                              hipStream_t stream)
{
    const float* tgt     = (const float*)d_in[0];  // data_input  [4,16,3,256,256]
    const float* out_img = (const float*)d_in[1];  // model_output
    float* partials = (float*)d_ws;                // 1024 floats

    canny_tile_kernel<<<NBLK, 256, 0, stream>>>(out_img, tgt, partials);
    final_reduce_kernel<<<1, 256, 0, stream>>>(partials, (float*)d_out);
}

// Round 2
// 174.819 us; speedup vs baseline: 2.1902x; 2.1902x over previous
//
#include <hip/hip_runtime.h>
#include <math.h>

#define HW   256
#define TR   16     // tile rows (owned)
#define TC   64     // tile cols (owned)
#define NBLK 4096   // 64 frames * 16 row-tiles * 4 col-tiles
#define BR   24     // hblur rows staged (TR + 2*4)
#define HC   68     // hblur cols / blur cols (TC + 2*2)
#define VR   20     // blur rows (TR + 2*2)
#define GR   18     // grad rows (TR + 2*1)
#define GC   66     // grad cols (TC + 2*1)

namespace {
// Gaussian(5, std=1) computed in float64 then cast, matching _gaussian_1d
constexpr double kE2  = 0.13533528323661269189;  // exp(-2)
constexpr double kE05 = 0.60653065971263342360;  // exp(-0.5)
constexpr double kSum = 1.0 + 2.0 * kE2 + 2.0 * kE05;
constexpr float G0f = (float)(kE2 / kSum);
constexpr float G1f = (float)(kE05 / kSum);
constexpr float G2f = (float)(1.0 / kSum);
constexpr float RAD2DEG = (float)(180.0 / 3.14159265358979323846);
}

// Neighbor offsets for direction k (cross-correlation with DIR_FILTERS):
// (dy,dx): k0(0,1) k1(1,1) k2(1,0) k3(1,-1) k4(0,-1) k5(-1,-1) k6(-1,0) k7(-1,1)
// Packed as nibbles ((dy+1)<<2)|(dx+1), k0 in the low nibble.
#define DIR_PACK 0x210489A6u

__global__ __launch_bounds__(256, 6)
void canny_tile_kernel(const float* __restrict__ imgA,
                       const float* __restrict__ imgB,
                       float* __restrict__ partials)
{
    __shared__ float s_tmp[BR * HC];   // horizontal gaussian
    __shared__ float s_blur[VR * HC];  // full blur (zero outside image)
    __shared__ float s_grad[GR * GC];  // channel-summed |grad| (zero outside image)
    __shared__ float s_red[4];

    const int tid  = threadIdx.x;
    const int bid  = blockIdx.x;
    const int n    = bid >> 6;           // frame 0..63
    const int tile = bid & 63;
    const int ty0  = (tile >> 2) * TR;   // 16 row-tiles
    const int tx0  = (tile & 3) * TC;    // 4 col-tiles

    const int ox  = tid & 63;            // owned column within tile
    const int oyb = tid >> 6;            // row group 0..3; owned rows oyb+4k, k=0..3

    float e_first[4];
    float acc = 0.0f;

    for (int img = 0; img < 2; ++img) {
        const float* base = (img == 0 ? imgA : imgB) + (size_t)n * 3 * (HW * HW);
        float gxs[4], gys[4];
        #pragma unroll
        for (int k = 0; k < 4; ++k) { gxs[k] = 0.0f; gys[k] = 0.0f; }

        for (int c = 0; c < 3; ++c) {
            const float* plane = base + c * (HW * HW);
            __syncthreads();  // protect s_tmp (read by prev A2) and s_grad (read by prev Phase B)

            // ---- A1: horizontal 5-tap gaussian -> s_tmp[BR][HC]
            // s_tmp[r][cx] = hblur(y = ty0-4+r, x = tx0-2+cx); zero for y outside image
            for (int i = tid; i < BR * HC; i += 256) {
                const int r  = i / HC;
                const int cx = i - r * HC;
                const int y  = ty0 - 4 + r;
                float h = 0.0f;
                if ((unsigned)y < HW) {
                    const float* row = plane + y * HW;
                    const int x0 = tx0 - 4 + cx;   // first tap
                    if (x0 >= 0 && x0 <= HW - 5) {
                        h = G0f * row[x0]     + G1f * row[x0 + 1] + G2f * row[x0 + 2]
                          + G1f * row[x0 + 3] + G0f * row[x0 + 4];
                    } else {
                        float v0 = ((unsigned)(x0    ) < HW) ? row[x0    ] : 0.0f;
                        float v1 = ((unsigned)(x0 + 1) < HW) ? row[x0 + 1] : 0.0f;
                        float v2 = ((unsigned)(x0 + 2) < HW) ? row[x0 + 2] : 0.0f;
                        float v3 = ((unsigned)(x0 + 3) < HW) ? row[x0 + 3] : 0.0f;
                        float v4 = ((unsigned)(x0 + 4) < HW) ? row[x0 + 4] : 0.0f;
                        h = G0f*v0 + G1f*v1 + G2f*v2 + G1f*v3 + G0f*v4;
                    }
                }
                s_tmp[i] = h;
            }
            __syncthreads();

            // ---- A2: vertical 5-tap gaussian -> s_blur[VR][HC]
            // Sobel zero-pads BLUR, so blur outside the image must be exactly 0.
            for (int i = tid; i < VR * HC; i += 256) {
                const int r  = i / HC;
                const int cx = i - r * HC;
                const int y  = ty0 - 2 + r;
                const int x  = tx0 - 2 + cx;
                float v = 0.0f;
                if ((unsigned)y < HW && (unsigned)x < HW) {
                    v = G0f * s_tmp[i]          + G1f * s_tmp[i + HC]
                      + G2f * s_tmp[i + 2 * HC] + G1f * s_tmp[i + 3 * HC]
                      + G0f * s_tmp[i + 4 * HC];
                }
                s_blur[i] = v;
            }
            __syncthreads();

            // ---- A3: sobel magnitude, accumulated over channels -> s_grad[GR][GC]
            // DIR conv zero-pads grad_mag, so grad outside the image must be 0.
            for (int i = tid; i < GR * GC; i += 256) {
                const int r  = i / GC;
                const int cc = i - r * GC;
                const int y  = ty0 - 1 + r;
                const int x  = tx0 - 1 + cc;
                float gmag = 0.0f;
                if ((unsigned)y < HW && (unsigned)x < HW) {
                    const float* b = &s_blur[r * HC + cc];
                    const float b00 = b[0],        b01 = b[1],          b02 = b[2];
                    const float b10 = b[HC],                            b12 = b[HC + 2];
                    const float b20 = b[2 * HC],   b21 = b[2 * HC + 1], b22 = b[2 * HC + 2];
                    const float gx = (b00 + 2.0f * b10 + b20) - (b02 + 2.0f * b12 + b22);
                    const float gy = (b00 + 2.0f * b01 + b02) - (b20 + 2.0f * b21 + b22);
                    gmag = sqrtf(gx * gx + gy * gy);
                }
                if (c == 0) s_grad[i] = gmag;
                else        s_grad[i] += gmag;
            }

            // ---- A4: accumulate channel-summed gx, gy at owned pixels (registers)
            #pragma unroll
            for (int k = 0; k < 4; ++k) {
                const int oy = oyb + 4 * k;
                const float* b = &s_blur[(oy + 1) * HC + (ox + 1)];
                const float b00 = b[0],        b01 = b[1],          b02 = b[2];
                const float b10 = b[HC],                            b12 = b[HC + 2];
                const float b20 = b[2 * HC],   b21 = b[2 * HC + 1], b22 = b[2 * HC + 2];
                gxs[k] += (b00 + 2.0f * b10 + b20) - (b02 + 2.0f * b12 + b22);
                gys[k] += (b00 + 2.0f * b01 + b02) - (b20 + 2.0f * b21 + b22);
            }
        }
        __syncthreads();  // s_grad complete for all channels

        // ---- Phase B: orientation NMS + threshold at owned 16x64 pixels
        #pragma unroll
        for (int k = 0; k < 4; ++k) {
            const int oy = oyb + 4 * k;
            const float gc    = s_grad[(oy + 1) * GC + (ox + 1)];
            const float theta = atan2f(gys[k], gxs[k]);
            const float ori   = theta * RAD2DEG + 180.0f;       // [0, 360]
            const float t     = rintf(ori / 45.0f);             // round-half-even, 0..8
            const int   kp    = ((int)t) & 7;                   // mod 8 (handles 8 -> 0)
            const unsigned e4 = (DIR_PACK >> (4 * kp)) & 15u;
            const int dy = (int)(e4 >> 2) - 1;
            const int dx = (int)(e4 & 3u) - 1;
            // neighbor at k+4 is exactly the negated offset
            const float pos = gc - s_grad[(oy + 1 + dy) * GC + (ox + 1 + dx)];
            const float neg = gc - s_grad[(oy + 1 - dy) * GC + (ox + 1 - dx)];
            const float thin = (fminf(pos, neg) > 0.0f) ? gc : 0.0f;
            const float e    = (thin < 2.0f) ? 0.0f : thin;
            if (img == 0) e_first[k] = e;
            else          acc += fabsf(e - e_first[k]);
        }
        __syncthreads();  // s_grad/s_tmp reused by next image
    }

    // ---- deterministic block reduction
    #pragma unroll
    for (int off = 32; off > 0; off >>= 1) acc += __shfl_down(acc, off, 64);
    if ((tid & 63) == 0) s_red[tid >> 6] = acc;
    __syncthreads();
    if (tid == 0) partials[bid] = (s_red[0] + s_red[1]) + (s_red[2] + s_red[3]);
}

__global__ void final_reduce_kernel(const float* __restrict__ partials,
                                    float* __restrict__ out)
{
    __shared__ float s_red[4];
    const int tid = threadIdx.x;  // 256 threads
    float v = 0.0f;
    #pragma unroll
    for (int j = 0; j < 16; ++j) v += partials[tid + 256 * j];
    #pragma unroll
    for (int off = 32; off > 0; off >>= 1) v += __shfl_down(v, off, 64);
    if ((tid & 63) == 0) s_red[tid >> 6] = v;
    __syncthreads();
    if (tid == 0)
        out[0] = ((s_red[0] + s_red[1]) + (s_red[2] + s_red[3])) * (1.0f / 4194304.0f);
}

extern "C" void kernel_launch(void* const* d_in, const int* in_sizes, int n_in,
                              void* d_out, int out_size, void* d_ws, size_t ws_size,
                              hipStream_t stream)
{
    const float* tgt     = (const float*)d_in[0];  // data_input  [4,16,3,256,256]
    const float* out_img = (const float*)d_in[1];  // model_output
    float* partials = (float*)d_ws;                // 4096 floats

    canny_tile_kernel<<<NBLK, 256, 0, stream>>>(out_img, tgt, partials);
    final_reduce_kernel<<<1, 256, 0, stream>>>(partials, (float*)d_out);
}

// Round 3
// 157.533 us; speedup vs baseline: 2.4305x; 1.1097x over previous
//
#include <hip/hip_runtime.h>
#include <math.h>

#define HW   256
#define TR   16     // tile rows (owned)
#define TC   64     // tile cols (owned)
#define NBLK 4096   // 64 frames * 16 row-tiles * 4 col-tiles
#define BR   24     // hblur rows staged (TR + 2*4)
#define HC   68     // hblur cols / blur cols (TC + 2*2)
#define VR   20     // blur rows (TR + 2*2)
#define GR   18     // grad rows (TR + 2*1)
#define GC   66     // grad cols (TC + 2*1)
#define NHALO 164   // perimeter of GR x GC grid: 2*66 + 2*16

namespace {
// Gaussian(5, std=1) computed in float64 then cast, matching _gaussian_1d
constexpr double kE2  = 0.13533528323661269189;  // exp(-2)
constexpr double kE05 = 0.60653065971263342360;  // exp(-0.5)
constexpr double kSum = 1.0 + 2.0 * kE2 + 2.0 * kE05;
constexpr float G0f = (float)(kE2 / kSum);
constexpr float G1f = (float)(kE05 / kSum);
constexpr float G2f = (float)(1.0 / kSum);
constexpr float T1  = 0.41421356237309503f;   // tan(22.5 deg)
constexpr float T2  = 2.41421356237309503f;   // tan(67.5 deg)
}

__global__ __launch_bounds__(256, 8)
void canny_tile_kernel(const float* __restrict__ imgA,
                       const float* __restrict__ imgB,
                       float* __restrict__ partials)
{
    __shared__ float s_tmp[BR * HC];   // horizontal gaussian
    __shared__ float s_blur[VR * HC];  // full blur (zero outside image)
    __shared__ float s_grad[GR * GC];  // channel-summed |grad| (zero outside image)
    __shared__ float s_red[4];

    const int tid  = threadIdx.x;
    const int bid  = blockIdx.x;
    const int n    = bid >> 6;           // frame 0..63
    const int tile = bid & 63;
    const int ty0  = (tile >> 2) * TR;   // 16 row-tiles
    const int tx0  = (tile & 3) * TC;    // 4 col-tiles

    const int ox  = tid & 63;            // owned column within tile
    const int oyb = tid >> 6;            // row group 0..3; owned rows oyb+4k, k=0..3

    // halo element (r,cc) for threads < NHALO (perimeter of GR x GC)
    int h_r = 0, h_cc = 0;
    if (tid < 66)        { h_r = 0;              h_cc = tid; }
    else if (tid < 132)  { h_r = GR - 1;         h_cc = tid - 66; }
    else if (tid < 148)  { h_r = tid - 132 + 1;  h_cc = 0; }
    else if (tid < NHALO){ h_r = tid - 148 + 1;  h_cc = GC - 1; }
    const bool has_halo = (tid < NHALO);
    const int  h_y = ty0 - 1 + h_r;
    const int  h_x = tx0 - 1 + h_cc;
    const bool h_in = ((unsigned)h_y < HW) && ((unsigned)h_x < HW);

    float e_first[4];
    float acc = 0.0f;

    for (int img = 0; img < 2; ++img) {
        const float* base = (img == 0 ? imgA : imgB) + (size_t)n * 3 * (HW * HW);
        float gxs[4], gys[4], gms[4];
        float hmag = 0.0f;
        #pragma unroll
        for (int k = 0; k < 4; ++k) { gxs[k] = 0.0f; gys[k] = 0.0f; gms[k] = 0.0f; }

        for (int c = 0; c < 3; ++c) {
            const float* plane = base + c * (HW * HW);
            __syncthreads();  // protect s_tmp (prev A2 readers) and s_grad (prev Phase B readers)

            // ---- A1: horizontal 5-tap gaussian -> s_tmp[BR][HC]
            // s_tmp[r][cx] = hblur(y = ty0-4+r, x = tx0-2+cx); zero for y outside image
            for (int i = tid; i < BR * HC; i += 256) {
                const int r  = i / HC;
                const int cx = i - r * HC;
                const int y  = ty0 - 4 + r;
                float h = 0.0f;
                if ((unsigned)y < HW) {
                    const float* row = plane + y * HW;
                    const int x0 = tx0 - 4 + cx;   // first tap
                    if (x0 >= 0 && x0 <= HW - 5) {
                        h = G0f * row[x0]     + G1f * row[x0 + 1] + G2f * row[x0 + 2]
                          + G1f * row[x0 + 3] + G0f * row[x0 + 4];
                    } else {
                        float v0 = ((unsigned)(x0    ) < HW) ? row[x0    ] : 0.0f;
                        float v1 = ((unsigned)(x0 + 1) < HW) ? row[x0 + 1] : 0.0f;
                        float v2 = ((unsigned)(x0 + 2) < HW) ? row[x0 + 2] : 0.0f;
                        float v3 = ((unsigned)(x0 + 3) < HW) ? row[x0 + 3] : 0.0f;
                        float v4 = ((unsigned)(x0 + 4) < HW) ? row[x0 + 4] : 0.0f;
                        h = G0f*v0 + G1f*v1 + G2f*v2 + G1f*v3 + G0f*v4;
                    }
                }
                s_tmp[i] = h;
            }
            __syncthreads();

            // ---- A2: vertical 5-tap gaussian -> s_blur[VR][HC]
            // Sobel zero-pads BLUR, so blur outside the image must be exactly 0.
            for (int i = tid; i < VR * HC; i += 256) {
                const int r  = i / HC;
                const int cx = i - r * HC;
                const int y  = ty0 - 2 + r;
                const int x  = tx0 - 2 + cx;
                float v = 0.0f;
                if ((unsigned)y < HW && (unsigned)x < HW) {
                    v = G0f * s_tmp[i]          + G1f * s_tmp[i + HC]
                      + G2f * s_tmp[i + 2 * HC] + G1f * s_tmp[i + 3 * HC]
                      + G0f * s_tmp[i + 4 * HC];
                }
                s_blur[i] = v;
            }
            __syncthreads();

            // ---- A3a: interior sobel at owned pixels -> registers + s_grad write
            // owned pixel (oy,ox) is grad elem (oy+1, ox+1); always inside image
            #pragma unroll
            for (int k = 0; k < 4; ++k) {
                const int oy = oyb + 4 * k;
                const float* b = &s_blur[(oy + 1) * HC + (ox + 1)];
                const float b00 = b[0],        b01 = b[1],          b02 = b[2];
                const float b10 = b[HC],                            b12 = b[HC + 2];
                const float b20 = b[2 * HC],   b21 = b[2 * HC + 1], b22 = b[2 * HC + 2];
                const float gx = (b00 + 2.0f * b10 + b20) - (b02 + 2.0f * b12 + b22);
                const float gy = (b00 + 2.0f * b01 + b02) - (b20 + 2.0f * b21 + b22);
                gxs[k] += gx;
                gys[k] += gy;
                gms[k] += sqrtf(gx * gx + gy * gy);
                s_grad[(oy + 1) * GC + (ox + 1)] = gms[k];
            }

            // ---- A3b: halo sobel (perimeter of GR x GC), one elem per thread
            if (has_halo) {
                float gmag = 0.0f;
                if (h_in) {
                    const float* b = &s_blur[h_r * HC + h_cc];
                    const float b00 = b[0],        b01 = b[1],          b02 = b[2];
                    const float b10 = b[HC],                            b12 = b[HC + 2];
                    const float b20 = b[2 * HC],   b21 = b[2 * HC + 1], b22 = b[2 * HC + 2];
                    const float gx = (b00 + 2.0f * b10 + b20) - (b02 + 2.0f * b12 + b22);
                    const float gy = (b00 + 2.0f * b01 + b02) - (b20 + 2.0f * b21 + b22);
                    gmag = sqrtf(gx * gx + gy * gy);
                }
                hmag += gmag;
                s_grad[h_r * GC + h_cc] = hmag;
            }
        }
        __syncthreads();  // s_grad complete for all channels

        // ---- Phase B: axis-based NMS + threshold at owned pixels
        // min(pos,neg) is symmetric in k -> k+4, so only the direction AXIS matters.
        // Nearest-45deg axis from |gy| vs tan(22.5)|gx| / tan(67.5)|gx| comparisons.
        #pragma unroll
        for (int k = 0; k < 4; ++k) {
            const int oy = oyb + 4 * k;
            const float gc = gms[k];
            const float gx = gxs[k], gy = gys[k];
            const float ax = fabsf(gx), ay = fabsf(gy);
            int dy, dx;
            if (ay <= T1 * ax)      { dy = 0; dx = 1; }   // near 0/180 deg
            else if (ay >= T2 * ax) { dy = 1; dx = 0; }   // near +-90 deg
            else                    { dy = 1; dx = ((gx > 0.0f) == (gy > 0.0f)) ? 1 : -1; }
            const int ci = (oy + 1) * GC + (ox + 1);
            const float pos = gc - s_grad[ci + dy * GC + dx];
            const float neg = gc - s_grad[ci - dy * GC - dx];
            const float thin = (fminf(pos, neg) > 0.0f) ? gc : 0.0f;
            const float e    = (thin < 2.0f) ? 0.0f : thin;
            if (img == 0) e_first[k] = e;
            else          acc += fabsf(e - e_first[k]);
        }
        __syncthreads();  // buffers reused by next image
    }

    // ---- deterministic block reduction
    #pragma unroll
    for (int off = 32; off > 0; off >>= 1) acc += __shfl_down(acc, off, 64);
    if ((tid & 63) == 0) s_red[tid >> 6] = acc;
    __syncthreads();
    if (tid == 0) partials[bid] = (s_red[0] + s_red[1]) + (s_red[2] + s_red[3]);
}

__global__ void final_reduce_kernel(const float* __restrict__ partials,
                                    float* __restrict__ out)
{
    __shared__ float s_red[4];
    const int tid = threadIdx.x;  // 256 threads
    float v = 0.0f;
    #pragma unroll
    for (int j = 0; j < 16; ++j) v += partials[tid + 256 * j];
    #pragma unroll
    for (int off = 32; off > 0; off >>= 1) v += __shfl_down(v, off, 64);
    if ((tid & 63) == 0) s_red[tid >> 6] = v;
    __syncthreads();
    if (tid == 0)
        out[0] = ((s_red[0] + s_red[1]) + (s_red[2] + s_red[3])) * (1.0f / 4194304.0f);
}

extern "C" void kernel_launch(void* const* d_in, const int* in_sizes, int n_in,
                              void* d_out, int out_size, void* d_ws, size_t ws_size,
                              hipStream_t stream)
{
    const float* tgt     = (const float*)d_in[0];  // data_input  [4,16,3,256,256]
    const float* out_img = (const float*)d_in[1];  // model_output
    float* partials = (float*)d_ws;                // 4096 floats

    canny_tile_kernel<<<NBLK, 256, 0, stream>>>(out_img, tgt, partials);
    final_reduce_kernel<<<1, 256, 0, stream>>>(partials, (float*)d_out);
}

// Round 4
// 76.975 us; speedup vs baseline: 4.9742x; 2.0466x over previous
//
#include <hip/hip_runtime.h>
#include <math.h>

#define HW   256
#define TR   16     // tile rows (owned)
#define TC   64     // tile cols (owned)
#define NBLK 4096   // 64 frames * 16 row-tiles * 4 col-tiles
#define BR   24     // hblur rows staged (TR + 2*4)
#define HC   68     // hblur/blur cols (TC + 2*2), multiple of 4
#define VR   20     // blur rows (TR + 2*2)
#define GR   18     // grad rows (TR + 2*1)
#define GC   66     // grad cols (TC + 2*1)
#define NHALO 164   // perimeter of GR x GC grid: 2*66 + 2*16
#define NG1  (BR * 17)  // 408 float4-groups in s_tmp
#define NG2  (VR * 17)  // 340 float4-groups in s_blur

namespace {
// Gaussian(5, std=1) computed in float64 then cast, matching _gaussian_1d
constexpr double kE2  = 0.13533528323661269189;  // exp(-2)
constexpr double kE05 = 0.60653065971263342360;  // exp(-0.5)
constexpr double kSum = 1.0 + 2.0 * kE2 + 2.0 * kE05;
constexpr float G0f = (float)(kE2 / kSum);
constexpr float G1f = (float)(kE05 / kSum);
constexpr float G2f = (float)(1.0 / kSum);
constexpr float T1  = 0.41421356237309503f;   // tan(22.5 deg)
constexpr float T2  = 2.41421356237309503f;   // tan(67.5 deg)
}

__global__ __launch_bounds__(256, 8)
void canny_tile_kernel(const float* __restrict__ imgA,
                       const float* __restrict__ imgB,
                       float* __restrict__ partials)
{
    __shared__ __align__(16) float s_tmp[BR * HC];   // horizontal gaussian
    __shared__ __align__(16) float s_blur[VR * HC];  // full blur (zero outside image)
    __shared__ float s_grad[GR * GC];                // channel-summed |grad|
    __shared__ float s_red[4];

    const int tid  = threadIdx.x;
    const int bid  = blockIdx.x;
    const int n    = bid >> 6;           // frame 0..63
    const int tile = bid & 63;
    const int ty0  = (tile >> 2) * TR;   // 16 row-tiles
    const int tx0  = (tile & 3) * TC;    // 4 col-tiles

    const int ox  = tid & 63;            // owned column within tile
    const int oy0 = (tid >> 6) * 4;      // owned rows oy0 .. oy0+3 (consecutive)

    // halo element (r,cc) for threads < NHALO (perimeter of GR x GC)
    int h_r = 0, h_cc = 0;
    if (tid < 66)        { h_r = 0;              h_cc = tid; }
    else if (tid < 132)  { h_r = GR - 1;         h_cc = tid - 66; }
    else if (tid < 148)  { h_r = tid - 132 + 1;  h_cc = 0; }
    else if (tid < NHALO){ h_r = tid - 148 + 1;  h_cc = GC - 1; }
    const bool has_halo = (tid < NHALO);
    const int  h_y = ty0 - 1 + h_r;
    const int  h_x = tx0 - 1 + h_cc;
    const bool h_in = ((unsigned)h_y < HW) && ((unsigned)h_x < HW);

    float e_first[4];
    float acc = 0.0f;

    for (int img = 0; img < 2; ++img) {
        const float* base = (img == 0 ? imgA : imgB) + (size_t)n * 3 * (HW * HW);
        float gxs[4], gys[4], gms[4];
        float hmag = 0.0f;
        #pragma unroll
        for (int k = 0; k < 4; ++k) { gxs[k] = 0.0f; gys[k] = 0.0f; gms[k] = 0.0f; }

        for (int c = 0; c < 3; ++c) {
            const float* plane = base + c * (HW * HW);

            // ---- A1: horizontal 5-tap gaussian, 4 outputs/group -> s_tmp[BR][HC]
            // s_tmp[r][cx] = hblur(y = ty0-4+r, x = tx0-2+cx); zero for y outside
            for (int g = tid; g < NG1; g += 256) {
                const int r  = g / 17;
                const int c4 = (g - r * 17) * 4;
                const int y  = ty0 - 4 + r;
                float4 o = make_float4(0.f, 0.f, 0.f, 0.f);
                if ((unsigned)y < HW) {
                    const int x0 = tx0 - 4 + c4;   // first tap of first output
                    const float* row = plane + y * HW;
                    if (x0 >= 0 && x0 <= HW - 8) {
                        const float4 a = *(const float4*)(row + x0);
                        const float4 b = *(const float4*)(row + x0 + 4);
                        o.x = G0f*a.x + G1f*a.y + G2f*a.z + G1f*a.w + G0f*b.x;
                        o.y = G0f*a.y + G1f*a.z + G2f*a.w + G1f*b.x + G0f*b.y;
                        o.z = G0f*a.z + G1f*a.w + G2f*b.x + G1f*b.y + G0f*b.z;
                        o.w = G0f*a.w + G1f*b.x + G2f*b.y + G1f*b.z + G0f*b.w;
                    } else {
                        float vv[8];
                        #pragma unroll
                        for (int j = 0; j < 8; ++j)
                            vv[j] = ((unsigned)(x0 + j) < HW) ? row[x0 + j] : 0.0f;
                        o.x = G0f*vv[0] + G1f*vv[1] + G2f*vv[2] + G1f*vv[3] + G0f*vv[4];
                        o.y = G0f*vv[1] + G1f*vv[2] + G2f*vv[3] + G1f*vv[4] + G0f*vv[5];
                        o.z = G0f*vv[2] + G1f*vv[3] + G2f*vv[4] + G1f*vv[5] + G0f*vv[6];
                        o.w = G0f*vv[3] + G1f*vv[4] + G2f*vv[5] + G1f*vv[6] + G0f*vv[7];
                    }
                }
                *(float4*)&s_tmp[r * HC + c4] = o;
            }
            __syncthreads();

            // ---- A2: vertical 5-tap gaussian, 4 outputs/group -> s_blur[VR][HC]
            // Sobel zero-pads BLUR, so blur outside the image must be exactly 0.
            for (int g = tid; g < NG2; g += 256) {
                const int r  = g / 17;
                const int c4 = (g - r * 17) * 4;
                const int y  = ty0 - 2 + r;
                float4 v = make_float4(0.f, 0.f, 0.f, 0.f);
                if ((unsigned)y < HW) {
                    const float4 t0 = *(const float4*)&s_tmp[(r    ) * HC + c4];
                    const float4 t1 = *(const float4*)&s_tmp[(r + 1) * HC + c4];
                    const float4 t2 = *(const float4*)&s_tmp[(r + 2) * HC + c4];
                    const float4 t3 = *(const float4*)&s_tmp[(r + 3) * HC + c4];
                    const float4 t4 = *(const float4*)&s_tmp[(r + 4) * HC + c4];
                    v.x = G0f*t0.x + G1f*t1.x + G2f*t2.x + G1f*t3.x + G0f*t4.x;
                    v.y = G0f*t0.y + G1f*t1.y + G2f*t2.y + G1f*t3.y + G0f*t4.y;
                    v.z = G0f*t0.z + G1f*t1.z + G2f*t2.z + G1f*t3.z + G0f*t4.z;
                    v.w = G0f*t0.w + G1f*t1.w + G2f*t2.w + G1f*t3.w + G0f*t4.w;
                    const int xb = tx0 - 2 + c4;
                    if (xb < 0 || xb > HW - 4) {   // only image-edge col groups
                        if ((unsigned)(xb + 0) >= HW) v.x = 0.f;
                        if ((unsigned)(xb + 1) >= HW) v.y = 0.f;
                        if ((unsigned)(xb + 2) >= HW) v.z = 0.f;
                        if ((unsigned)(xb + 3) >= HW) v.w = 0.f;
                    }
                }
                *(float4*)&s_blur[r * HC + c4] = v;
            }
            __syncthreads();

            // ---- A3a: interior sobel via row-sum factoring (4 consecutive rows)
            // owned pixel (oy,ox) = grad elem (oy+1, ox+1); blur rows oy+1..oy+3,
            // cols ox+1..ox+3 (center = s_blur[oy+2][ox+2] = pixel (ty0+oy, tx0+ox))
            {
                float cd[6], rs[6];
                #pragma unroll
                for (int r = 0; r < 6; ++r) {
                    const float* b = &s_blur[(oy0 + 1 + r) * HC + (ox + 1)];
                    const float bl = b[0], bc = b[1], br = b[2];
                    cd[r] = bl - br;
                    rs[r] = bl + 2.0f * bc + br;
                }
                #pragma unroll
                for (int k = 0; k < 4; ++k) {
                    const float gx = cd[k] + 2.0f * cd[k + 1] + cd[k + 2];
                    const float gy = rs[k] - rs[k + 2];
                    gxs[k] += gx;
                    gys[k] += gy;
                    gms[k] += sqrtf(gx * gx + gy * gy);
                    s_grad[(oy0 + k + 1) * GC + (ox + 1)] = gms[k];
                }
            }

            // ---- A3b: halo sobel (perimeter of GR x GC), one elem per thread
            if (has_halo) {
                float gmag = 0.0f;
                if (h_in) {
                    const float* b = &s_blur[h_r * HC + h_cc];
                    const float b00 = b[0],        b01 = b[1],          b02 = b[2];
                    const float b10 = b[HC],                            b12 = b[HC + 2];
                    const float b20 = b[2 * HC],   b21 = b[2 * HC + 1], b22 = b[2 * HC + 2];
                    const float gx = (b00 + 2.0f * b10 + b20) - (b02 + 2.0f * b12 + b22);
                    const float gy = (b00 + 2.0f * b01 + b02) - (b20 + 2.0f * b21 + b22);
                    gmag = sqrtf(gx * gx + gy * gy);
                }
                hmag += gmag;
                s_grad[h_r * GC + h_cc] = hmag;
            }
            // no sync here: next A1 writes only s_tmp, whose readers (A2) are
            // already fenced by the post-A2 sync; A3 readers fenced below.
        }
        __syncthreads();  // s_grad complete for all channels

        // ---- Phase B: axis-based NMS + threshold at owned pixels
        // min(pos,neg) is symmetric in k -> k+4, so only the direction AXIS matters.
        #pragma unroll
        for (int k = 0; k < 4; ++k) {
            const int oy = oy0 + k;
            const float gc = gms[k];
            const float gx = gxs[k], gy = gys[k];
            const float ax = fabsf(gx), ay = fabsf(gy);
            int dy, dx;
            if (ay <= T1 * ax)      { dy = 0; dx = 1; }   // near 0/180 deg
            else if (ay >= T2 * ax) { dy = 1; dx = 0; }   // near +-90 deg
            else                    { dy = 1; dx = ((gx > 0.0f) == (gy > 0.0f)) ? 1 : -1; }
            const int ci = (oy + 1) * GC + (ox + 1);
            const float pos = gc - s_grad[ci + dy * GC + dx];
            const float neg = gc - s_grad[ci - dy * GC - dx];
            const float thin = (fminf(pos, neg) > 0.0f) ? gc : 0.0f;
            const float e    = (thin < 2.0f) ? 0.0f : thin;
            if (img == 0) e_first[k] = e;
            else          acc += fabsf(e - e_first[k]);
        }
        // no sync here: next img's A3 s_grad writes are fenced by two
        // intervening syncs (post-A1, post-A2) before they can occur.
    }

    // ---- deterministic block reduction
    #pragma unroll
    for (int off = 32; off > 0; off >>= 1) acc += __shfl_down(acc, off, 64);
    if ((tid & 63) == 0) s_red[tid >> 6] = acc;
    __syncthreads();
    if (tid == 0) partials[bid] = (s_red[0] + s_red[1]) + (s_red[2] + s_red[3]);
}

__global__ void final_reduce_kernel(const float* __restrict__ partials,
                                    float* __restrict__ out)
{
    __shared__ float s_red[4];
    const int tid = threadIdx.x;  // 256 threads
    float v = 0.0f;
    #pragma unroll
    for (int j = 0; j < 16; ++j) v += partials[tid + 256 * j];
    #pragma unroll
    for (int off = 32; off > 0; off >>= 1) v += __shfl_down(v, off, 64);
    if ((tid & 63) == 0) s_red[tid >> 6] = v;
    __syncthreads();
    if (tid == 0)
        out[0] = ((s_red[0] + s_red[1]) + (s_red[2] + s_red[3])) * (1.0f / 4194304.0f);
}

extern "C" void kernel_launch(void* const* d_in, const int* in_sizes, int n_in,
                              void* d_out, int out_size, void* d_ws, size_t ws_size,
                              hipStream_t stream)
{
    const float* tgt     = (const float*)d_in[0];  // data_input  [4,16,3,256,256]
    const float* out_img = (const float*)d_in[1];  // model_output
    float* partials = (float*)d_ws;                // 4096 floats

    canny_tile_kernel<<<NBLK, 256, 0, stream>>>(out_img, tgt, partials);
    final_reduce_kernel<<<1, 256, 0, stream>>>(partials, (float*)d_out);
}